// Round 2
// baseline (714.586 us; speedup 1.0000x reference)
//
#include <hip/hip_runtime.h>

#define N_FEAT 128
#define F1 16
#define F2 2
#define XPAD 132
#define NPB 512          // nodes per bucket (power of two)
#define NPB_SHIFT 9
#define BMAX 256         // max buckets -> supports N <= 131072
#define CHUNK 8192       // edges per binning block

// ---------------- degree (global atomics) + bucket histogram (LDS -> global) ----------------
__global__ __launch_bounds__(256) void deghist_kernel(const int* __restrict__ col, int E,
        int* __restrict__ deg, int* __restrict__ bcnt) {
    __shared__ int hist[BMAX];
    int t = threadIdx.x;
    hist[t] = 0;
    __syncthreads();
    int e0 = (blockIdx.x * 256 + t) * 4;
    if (e0 + 3 < E) {
        int4 c = *(const int4*)(col + e0);
        atomicAdd(&deg[c.x], 1); atomicAdd(&hist[c.x >> NPB_SHIFT], 1);
        atomicAdd(&deg[c.y], 1); atomicAdd(&hist[c.y >> NPB_SHIFT], 1);
        atomicAdd(&deg[c.z], 1); atomicAdd(&hist[c.z >> NPB_SHIFT], 1);
        atomicAdd(&deg[c.w], 1); atomicAdd(&hist[c.w >> NPB_SHIFT], 1);
    } else {
        for (int e = e0; e < E; ++e) {
            int c = col[e];
            atomicAdd(&deg[c], 1); atomicAdd(&hist[c >> NPB_SHIFT], 1);
        }
    }
    __syncthreads();
    if (hist[t]) atomicAdd(&bcnt[t], hist[t]);
}

__global__ void dinv_kernel(const int* __restrict__ deg, float* __restrict__ dinv, int N) {
    int i = blockIdx.x * blockDim.x + threadIdx.x;
    if (i < N) dinv[i] = rsqrtf((float)(deg[i] + 1));  // +1 self loop
}

// ---------------- exclusive scan of bucket counts (single block) ----------------
__global__ __launch_bounds__(256) void bscan_kernel(const int* __restrict__ bcnt,
        int* __restrict__ bstart, int* __restrict__ gcur, int E, int nbuck) {
    __shared__ int s[BMAX];
    int t = threadIdx.x;
    int v = (t < nbuck) ? bcnt[t] : 0;
    s[t] = v;
    __syncthreads();
    for (int off = 1; off < BMAX; off <<= 1) {
        int a = (t >= off) ? s[t - off] : 0;
        __syncthreads();
        s[t] += a;
        __syncthreads();
    }
    int excl = s[t] - v;
    if (t < nbuck) { bstart[t] = excl; gcur[t] = excl; }
    if (t == 0) bstart[nbuck] = E;
}

// ---------------- bin edges into buckets, LDS-staged for coalesced write-out ----------------
// ebin word = (src << NPB_SHIFT) | (dst & (NPB-1)), grouped by bucket = dst >> NPB_SHIFT
__global__ __launch_bounds__(256) void bin_kernel(const int* __restrict__ rowi,
        const int* __restrict__ coli, int* __restrict__ gcur,
        int* __restrict__ ebin, int E) {
    __shared__ int stage[CHUNK];
    __shared__ unsigned char sbkt[CHUNK];
    __shared__ int cnt[BMAX];
    __shared__ int pos[BMAX];
    __shared__ int runb[BMAX];
    int t = threadIdx.x;
    int base = blockIdx.x * CHUNK;
    int nval = E - base; if (nval > CHUNK) nval = CHUNK;
    cnt[t] = 0;
    __syncthreads();

    int cbuf[32];
#pragma unroll
    for (int j = 0; j < 8; ++j) {
        int idx = base + ((j << 8) + t) * 4;
        if (idx + 3 < E) {
            int4 c4 = *(const int4*)(coli + idx);
            cbuf[j * 4 + 0] = c4.x; cbuf[j * 4 + 1] = c4.y;
            cbuf[j * 4 + 2] = c4.z; cbuf[j * 4 + 3] = c4.w;
        } else {
#pragma unroll
            for (int u = 0; u < 4; ++u) {
                int i2 = idx + u;
                cbuf[j * 4 + u] = (i2 < E) ? coli[i2] : -1;
            }
        }
    }
#pragma unroll
    for (int k = 0; k < 32; ++k)
        if (cbuf[k] >= 0) atomicAdd(&cnt[cbuf[k] >> NPB_SHIFT], 1);
    __syncthreads();

    // inclusive scan of cnt into pos
    pos[t] = cnt[t];
    __syncthreads();
    for (int off = 1; off < BMAX; off <<= 1) {
        int a = (t >= off) ? pos[t - off] : 0;
        __syncthreads();
        pos[t] += a;
        __syncthreads();
    }
    int myc = cnt[t];
    int excl = pos[t] - myc;
    if (myc > 0) {
        int g = atomicAdd(&gcur[t], myc);
        runb[t] = g - excl;   // final addr for LDS slot i of bucket t = runb[t] + i
    }
    __syncthreads();
    cnt[t] = excl;            // scatter cursor
    __syncthreads();

#pragma unroll
    for (int j = 0; j < 8; ++j) {
        int idx = base + ((j << 8) + t) * 4;
        int rr[4];
        if (idx + 3 < E) {
            int4 r4 = *(const int4*)(rowi + idx);
            rr[0] = r4.x; rr[1] = r4.y; rr[2] = r4.z; rr[3] = r4.w;
        } else {
#pragma unroll
            for (int u = 0; u < 4; ++u) {
                int i2 = idx + u;
                rr[u] = (i2 < E) ? rowi[i2] : 0;
            }
        }
#pragma unroll
        for (int u = 0; u < 4; ++u) {
            int c = cbuf[j * 4 + u];
            if (c >= 0) {
                int b = c >> NPB_SHIFT;
                int lp = atomicAdd(&cnt[b], 1);
                stage[lp] = (rr[u] << NPB_SHIFT) | (c & (NPB - 1));
                sbkt[lp] = (unsigned char)b;
            }
        }
    }
    __syncthreads();
    // bucket-sorted, lane-consecutive write-out
    for (int i = t; i < nval; i += 256)
        ebin[runb[sbkt[i]] + i] = stage[i];
}

// ---------------- layer-1 GEMM: hs[r,f] = dinv[r] * sum_k x[r,k]*W1[k,f] ----------------
__global__ __launch_bounds__(256) void gemm1_kernel(
    const float* __restrict__ x, const float* __restrict__ W1,
    const float* __restrict__ dinv, float* __restrict__ hs, int N) {
    __shared__ __align__(16) float wsT[F1][XPAD];   // wsT[f][k] = W1[k][f]
    __shared__ __align__(16) float xs[16][XPAD];
    int t = threadIdx.x;
    for (int i = t; i < N_FEAT * F1; i += 256) {
        int k = i >> 4, f = i & 15;
        wsT[f][k] = W1[i];
    }
    int row0 = blockIdx.x * 16;
    for (int i = t; i < 16 * (N_FEAT / 4); i += 256) {
        int r = i >> 5, k4 = i & 31;
        int row = row0 + r;
        float4 v = (row < N) ? ((const float4*)(x + (size_t)row * N_FEAT))[k4]
                             : make_float4(0.f, 0.f, 0.f, 0.f);
        *(float4*)&xs[r][k4 * 4] = v;
    }
    __syncthreads();
    int rr = t >> 4, f = t & 15;
    int row = row0 + rr;
    if (row >= N) return;
    float acc = 0.f;
#pragma unroll
    for (int k4 = 0; k4 < 32; ++k4) {
        float4 xv = *(const float4*)&xs[rr][k4 * 4];
        float4 wv = *(const float4*)&wsT[f][k4 * 4];
        acc += xv.x * wv.x + xv.y * wv.y + xv.z * wv.z + xv.w * wv.w;
    }
    hs[(size_t)row * F1 + f] = acc * dinv[row];
}

// ------- layer-1 aggregate: per-bucket LDS accumulator + fused bias/relu/W2 -------
__global__ __launch_bounds__(512) void agg1_kernel(const int* __restrict__ bstart,
        const int* __restrict__ ebin, const float* __restrict__ hs,
        const float* __restrict__ dinv, const float* __restrict__ b1,
        const float* __restrict__ W2, float* __restrict__ hs2, int N) {
    __shared__ float acc[NPB * 17];   // stride 17 breaks bank conflicts
    int t = threadIdx.x;
    int b = blockIdx.x;
    for (int i = t; i < NPB * 17; i += 512) acc[i] = 0.f;
    __syncthreads();
    int s = bstart[b], e = bstart[b + 1];
    int q = t & 3;
    int lane0 = t >> 2;
    const float4* hs4 = (const float4*)hs;
    for (int i = s + lane0; i < e; i += 256) {   // unroll-2: i and i+128
        int w0 = ebin[i];
        int i1 = i + 128;
        int w1 = (i1 < e) ? ebin[i1] : -1;
        int r0 = w0 >> NPB_SHIFT, c0 = w0 & (NPB - 1);
        float4 v0 = hs4[r0 * 4 + q];
        if (w1 >= 0) {
            int r1 = w1 >> NPB_SHIFT, c1 = w1 & (NPB - 1);
            float4 v1 = hs4[r1 * 4 + q];
            float* a0 = &acc[c0 * 17 + q * 4];
            atomicAdd(a0 + 0, v0.x); atomicAdd(a0 + 1, v0.y);
            atomicAdd(a0 + 2, v0.z); atomicAdd(a0 + 3, v0.w);
            float* a1 = &acc[c1 * 17 + q * 4];
            atomicAdd(a1 + 0, v1.x); atomicAdd(a1 + 1, v1.y);
            atomicAdd(a1 + 2, v1.z); atomicAdd(a1 + 3, v1.w);
        } else {
            float* a0 = &acc[c0 * 17 + q * 4];
            atomicAdd(a0 + 0, v0.x); atomicAdd(a0 + 1, v0.y);
            atomicAdd(a0 + 2, v0.z); atomicAdd(a0 + 3, v0.w);
        }
    }
    __syncthreads();
    int n0 = b << NPB_SHIFT;
    int f0 = q * 4;
    float bb0 = b1[f0 + 0], bb1 = b1[f0 + 1], bb2 = b1[f0 + 2], bb3 = b1[f0 + 3];
    float wa0 = W2[(f0 + 0) * F2 + 0], wb0 = W2[(f0 + 0) * F2 + 1];
    float wa1 = W2[(f0 + 1) * F2 + 0], wb1 = W2[(f0 + 1) * F2 + 1];
    float wa2 = W2[(f0 + 2) * F2 + 0], wb2 = W2[(f0 + 2) * F2 + 1];
    float wa3 = W2[(f0 + 3) * F2 + 0], wb3 = W2[(f0 + 3) * F2 + 1];
    for (int n = lane0; n < NPB; n += 128) {
        int node = n0 + n;
        if (node < N) {
            float di = dinv[node];
            float4 sv = hs4[node * 4 + q];      // self loop
            float x0 = acc[n * 17 + f0 + 0] + sv.x;
            float x1 = acc[n * 17 + f0 + 1] + sv.y;
            float x2 = acc[n * 17 + f0 + 2] + sv.z;
            float x3 = acc[n * 17 + f0 + 3] + sv.w;
            float o0 = fmaxf(di * x0 + bb0, 0.f);
            float o1 = fmaxf(di * x1 + bb1, 0.f);
            float o2 = fmaxf(di * x2 + bb2, 0.f);
            float o3 = fmaxf(di * x3 + bb3, 0.f);
            float h0 = o0 * wa0 + o1 * wa1 + o2 * wa2 + o3 * wa3;
            float h1 = o0 * wb0 + o1 * wb1 + o2 * wb2 + o3 * wb3;
            h0 += __shfl_xor(h0, 1); h0 += __shfl_xor(h0, 2);
            h1 += __shfl_xor(h1, 1); h1 += __shfl_xor(h1, 2);
            if (q == 0) *(float2*)&hs2[(size_t)node * 2] = make_float2(di * h0, di * h1);
        }
    }
}

// ------- layer-2 aggregate: per-bucket LDS accumulator + finalize -------
__global__ __launch_bounds__(512) void agg2_kernel(const int* __restrict__ bstart,
        const int* __restrict__ ebin, const float* __restrict__ hs2,
        const float* __restrict__ dinv, const float* __restrict__ b2,
        float* __restrict__ out, int N) {
    __shared__ float acc[NPB * 3];
    int t = threadIdx.x;
    int b = blockIdx.x;
    for (int i = t; i < NPB * 3; i += 512) acc[i] = 0.f;
    __syncthreads();
    int s = bstart[b], e = bstart[b + 1];
    for (int i = s + t; i < e; i += 512) {
        int w = ebin[i];
        int r = w >> NPB_SHIFT, cl = w & (NPB - 1);
        float2 hv = *(const float2*)&hs2[(size_t)r * 2];
        atomicAdd(&acc[cl * 3 + 0], hv.x);
        atomicAdd(&acc[cl * 3 + 1], hv.y);
    }
    __syncthreads();
    int n0 = b << NPB_SHIFT;
    int j = t & 1;
    float bj = b2[j];
    for (int n = t >> 1; n < NPB; n += 256) {
        int node = n0 + n;
        if (node < N)
            out[(size_t)node * 2 + j] =
                dinv[node] * (acc[n * 3 + j] + hs2[(size_t)node * 2 + j]) + bj;
    }
}

extern "C" void kernel_launch(void* const* d_in, const int* in_sizes, int n_in,
                              void* d_out, int out_size, void* d_ws, size_t ws_size,
                              hipStream_t stream) {
    const float* x  = (const float*)d_in[0];
    const int*   ei = (const int*)d_in[1];
    const float* W1 = (const float*)d_in[2];
    const float* b1 = (const float*)d_in[3];
    const float* W2 = (const float*)d_in[4];
    const float* b2 = (const float*)d_in[5];
    int N = in_sizes[0] / N_FEAT;
    int E = in_sizes[1] / 2;
    const int* rowi = ei;        // edge_index[0] = src
    const int* coli = ei + E;    // edge_index[1] = dst
    float* out = (float*)d_out;

    int nbuck = (N + NPB - 1) >> NPB_SHIFT;   // 196 for N=100000 (<= BMAX)

    // workspace layout (4B units)
    size_t NP = ((size_t)N + 1023) & ~(size_t)1023;
    int*   wsI    = (int*)d_ws;
    int*   deg    = wsI;                          // NP
    float* dinv   = (float*)(wsI + NP);           // NP
    int*   bcnt   = wsI + 2 * NP;                 // 512
    int*   bstart = wsI + 2 * NP + 512;           // 512 (nbuck+1 used)
    int*   gcur   = wsI + 2 * NP + 1024;          // 512
    float* hs     = (float*)(wsI + 2 * NP + 2048);// 16*NP
    float* hs2    = hs + 16 * NP;                 // 2*NP
    int*   ebin   = (int*)(hs2 + 2 * NP);         // E

    hipMemsetAsync(deg, 0, (size_t)N * sizeof(int), stream);
    hipMemsetAsync(bcnt, 0, BMAX * sizeof(int), stream);

    deghist_kernel<<<((E + 3) / 4 + 255) / 256, 256, 0, stream>>>(coli, E, deg, bcnt);
    dinv_kernel<<<(N + 255) / 256, 256, 0, stream>>>(deg, dinv, N);
    bscan_kernel<<<1, BMAX, 0, stream>>>(bcnt, bstart, gcur, E, nbuck);
    bin_kernel<<<(E + CHUNK - 1) / CHUNK, 256, 0, stream>>>(rowi, coli, gcur, ebin, E);
    gemm1_kernel<<<(N + 15) / 16, 256, 0, stream>>>(x, W1, dinv, hs, N);
    agg1_kernel<<<nbuck, 512, 0, stream>>>(bstart, ebin, hs, dinv, b1, W2, hs2, N);
    agg2_kernel<<<nbuck, 512, 0, stream>>>(bstart, ebin, hs2, dinv, b2, out, N);
}

// Round 3
// 678.261 us; speedup vs baseline: 1.0536x; 1.0536x over previous
//
#include <hip/hip_runtime.h>

#define N_FEAT 128
#define F1 16
#define F2 2
#define XPAD 132
#define NPB 512          // nodes per bucket (power of two)
#define NPB_SHIFT 9
#define BMAX 256         // max buckets -> supports N <= 131072
#define CHUNK 8192       // edges per binning block

// ---------------- degree (global atomics) + bucket histogram (LDS -> global) ----------------
__global__ __launch_bounds__(256) void deghist_kernel(const int* __restrict__ col, int E,
        int* __restrict__ deg, int* __restrict__ bcnt) {
    __shared__ int hist[BMAX];
    int t = threadIdx.x;
    hist[t] = 0;
    __syncthreads();
    int e0 = (blockIdx.x * 256 + t) * 4;
    if (e0 + 3 < E) {
        int4 c = *(const int4*)(col + e0);
        atomicAdd(&deg[c.x], 1); atomicAdd(&hist[c.x >> NPB_SHIFT], 1);
        atomicAdd(&deg[c.y], 1); atomicAdd(&hist[c.y >> NPB_SHIFT], 1);
        atomicAdd(&deg[c.z], 1); atomicAdd(&hist[c.z >> NPB_SHIFT], 1);
        atomicAdd(&deg[c.w], 1); atomicAdd(&hist[c.w >> NPB_SHIFT], 1);
    } else {
        for (int e = e0; e < E; ++e) {
            int c = col[e];
            atomicAdd(&deg[c], 1); atomicAdd(&hist[c >> NPB_SHIFT], 1);
        }
    }
    __syncthreads();
    if (hist[t]) atomicAdd(&bcnt[t], hist[t]);
}

__global__ void dinv_kernel(const int* __restrict__ deg, float* __restrict__ dinv, int N) {
    int i = blockIdx.x * blockDim.x + threadIdx.x;
    if (i < N) dinv[i] = rsqrtf((float)(deg[i] + 1));  // +1 self loop
}

// ---------------- exclusive scan of bucket counts (single block) ----------------
__global__ __launch_bounds__(256) void bscan_kernel(const int* __restrict__ bcnt,
        int* __restrict__ bstart, int* __restrict__ gcur, int E, int nbuck) {
    __shared__ int s[BMAX];
    int t = threadIdx.x;
    int v = (t < nbuck) ? bcnt[t] : 0;
    s[t] = v;
    __syncthreads();
    for (int off = 1; off < BMAX; off <<= 1) {
        int a = (t >= off) ? s[t - off] : 0;
        __syncthreads();
        s[t] += a;
        __syncthreads();
    }
    int excl = s[t] - v;
    if (t < nbuck) { bstart[t] = excl; gcur[t] = excl; }
    if (t == 0) bstart[nbuck] = E;
}

// ---------------- bin edges into buckets, LDS-staged for coalesced write-out ----------------
// ebin word = (src << NPB_SHIFT) | (dst & (NPB-1)), grouped by bucket = dst >> NPB_SHIFT
__global__ __launch_bounds__(256) void bin_kernel(const int* __restrict__ rowi,
        const int* __restrict__ coli, int* __restrict__ gcur,
        int* __restrict__ ebin, int E) {
    __shared__ int stage[CHUNK];
    __shared__ unsigned char sbkt[CHUNK];
    __shared__ int cnt[BMAX];
    __shared__ int pos[BMAX];
    __shared__ int runb[BMAX];
    int t = threadIdx.x;
    int base = blockIdx.x * CHUNK;
    int nval = E - base; if (nval > CHUNK) nval = CHUNK;
    cnt[t] = 0;
    __syncthreads();

    int cbuf[32];
#pragma unroll
    for (int j = 0; j < 8; ++j) {
        int idx = base + ((j << 8) + t) * 4;
        if (idx + 3 < E) {
            int4 c4 = *(const int4*)(coli + idx);
            cbuf[j * 4 + 0] = c4.x; cbuf[j * 4 + 1] = c4.y;
            cbuf[j * 4 + 2] = c4.z; cbuf[j * 4 + 3] = c4.w;
        } else {
#pragma unroll
            for (int u = 0; u < 4; ++u) {
                int i2 = idx + u;
                cbuf[j * 4 + u] = (i2 < E) ? coli[i2] : -1;
            }
        }
    }
#pragma unroll
    for (int k = 0; k < 32; ++k)
        if (cbuf[k] >= 0) atomicAdd(&cnt[cbuf[k] >> NPB_SHIFT], 1);
    __syncthreads();

    // inclusive scan of cnt into pos
    pos[t] = cnt[t];
    __syncthreads();
    for (int off = 1; off < BMAX; off <<= 1) {
        int a = (t >= off) ? pos[t - off] : 0;
        __syncthreads();
        pos[t] += a;
        __syncthreads();
    }
    int myc = cnt[t];
    int excl = pos[t] - myc;
    if (myc > 0) {
        int g = atomicAdd(&gcur[t], myc);
        runb[t] = g - excl;   // final addr for LDS slot i of bucket t = runb[t] + i
    }
    __syncthreads();
    cnt[t] = excl;            // scatter cursor
    __syncthreads();

#pragma unroll
    for (int j = 0; j < 8; ++j) {
        int idx = base + ((j << 8) + t) * 4;
        int rr[4];
        if (idx + 3 < E) {
            int4 r4 = *(const int4*)(rowi + idx);
            rr[0] = r4.x; rr[1] = r4.y; rr[2] = r4.z; rr[3] = r4.w;
        } else {
#pragma unroll
            for (int u = 0; u < 4; ++u) {
                int i2 = idx + u;
                rr[u] = (i2 < E) ? rowi[i2] : 0;
            }
        }
#pragma unroll
        for (int u = 0; u < 4; ++u) {
            int c = cbuf[j * 4 + u];
            if (c >= 0) {
                int b = c >> NPB_SHIFT;
                int lp = atomicAdd(&cnt[b], 1);
                stage[lp] = (rr[u] << NPB_SHIFT) | (c & (NPB - 1));
                sbkt[lp] = (unsigned char)b;
            }
        }
    }
    __syncthreads();
    // bucket-sorted, lane-consecutive write-out
    for (int i = t; i < nval; i += 256)
        ebin[runb[sbkt[i]] + i] = stage[i];
}

// ---------------- layer-1 GEMM: hs[r,f] = dinv[r] * sum_k x[r,k]*W1[k,f] ----------------
__global__ __launch_bounds__(256) void gemm1_kernel(
    const float* __restrict__ x, const float* __restrict__ W1,
    const float* __restrict__ dinv, float* __restrict__ hs, int N) {
    __shared__ __align__(16) float wsT[F1][XPAD];   // wsT[f][k] = W1[k][f]
    __shared__ __align__(16) float xs[16][XPAD];
    int t = threadIdx.x;
    for (int i = t; i < N_FEAT * F1; i += 256) {
        int k = i >> 4, f = i & 15;
        wsT[f][k] = W1[i];
    }
    int row0 = blockIdx.x * 16;
    for (int i = t; i < 16 * (N_FEAT / 4); i += 256) {
        int r = i >> 5, k4 = i & 31;
        int row = row0 + r;
        float4 v = (row < N) ? ((const float4*)(x + (size_t)row * N_FEAT))[k4]
                             : make_float4(0.f, 0.f, 0.f, 0.f);
        *(float4*)&xs[r][k4 * 4] = v;
    }
    __syncthreads();
    int rr = t >> 4, f = t & 15;
    int row = row0 + rr;
    if (row >= N) return;
    float acc = 0.f;
#pragma unroll
    for (int k4 = 0; k4 < 32; ++k4) {
        float4 xv = *(const float4*)&xs[rr][k4 * 4];
        float4 wv = *(const float4*)&wsT[f][k4 * 4];
        acc += xv.x * wv.x + xv.y * wv.y + xv.z * wv.z + xv.w * wv.w;
    }
    hs[(size_t)row * F1 + f] = acc * dinv[row];
}

// ------- layer-1 aggregate, split-K: each block does one slice of one bucket -------
__global__ __launch_bounds__(512) void agg1_part_kernel(const int* __restrict__ bstart,
        const int* __restrict__ ebin, const float* __restrict__ hs,
        float* __restrict__ part1, int K) {
    __shared__ float acc[NPB * 17];   // stride 17 breaks bank conflicts
    int t = threadIdx.x;
    int bid = blockIdx.x;
    int b = bid / K, slice = bid % K;
    for (int i = t; i < NPB * 17; i += 512) acc[i] = 0.f;
    __syncthreads();
    int s = bstart[b], e = bstart[b + 1];
    int len = e - s;
    int per = (len + K - 1) / K;
    int s0 = s + slice * per;
    int e0 = s0 + per; if (e0 > e) e0 = e;
    int q = t & 3;
    int lane0 = t >> 2;
    const float4* hs4 = (const float4*)hs;
    for (int i = s0 + lane0; i < e0; i += 256) {   // unroll-2: i and i+128
        int w0 = ebin[i];
        int i1 = i + 128;
        int w1 = (i1 < e0) ? ebin[i1] : -1;
        int r0 = w0 >> NPB_SHIFT, c0 = w0 & (NPB - 1);
        float4 v0 = hs4[(size_t)r0 * 4 + q];
        if (w1 >= 0) {
            int r1 = w1 >> NPB_SHIFT, c1 = w1 & (NPB - 1);
            float4 v1 = hs4[(size_t)r1 * 4 + q];
            float* a0 = &acc[c0 * 17 + q * 4];
            atomicAdd(a0 + 0, v0.x); atomicAdd(a0 + 1, v0.y);
            atomicAdd(a0 + 2, v0.z); atomicAdd(a0 + 3, v0.w);
            float* a1 = &acc[c1 * 17 + q * 4];
            atomicAdd(a1 + 0, v1.x); atomicAdd(a1 + 1, v1.y);
            atomicAdd(a1 + 2, v1.z); atomicAdd(a1 + 3, v1.w);
        } else {
            float* a0 = &acc[c0 * 17 + q * 4];
            atomicAdd(a0 + 0, v0.x); atomicAdd(a0 + 1, v0.y);
            atomicAdd(a0 + 2, v0.z); atomicAdd(a0 + 3, v0.w);
        }
    }
    __syncthreads();
    // flush partial: 512 nodes x 16 feats, contiguous per block
    float4* p4 = (float4*)(part1 + (size_t)bid * (NPB * F1));
    for (int i = t; i < NPB * F1 / 4; i += 512) {
        int n = i >> 2, f0 = (i & 3) * 4;
        p4[i] = make_float4(acc[n * 17 + f0 + 0], acc[n * 17 + f0 + 1],
                            acc[n * 17 + f0 + 2], acc[n * 17 + f0 + 3]);
    }
}

// ------- layer-1 combine partials + self + bias + relu + W2 -> hs2 -------
__global__ __launch_bounds__(256) void fuse1_kernel(const float* __restrict__ part1,
        const float* __restrict__ hs, const float* __restrict__ dinv,
        const float* __restrict__ b1, const float* __restrict__ W2,
        float* __restrict__ hs2, int N, int K) {
    int t = blockIdx.x * 256 + threadIdx.x;
    int g = t >> 2;       // node
    int q = t & 3;        // feature quad
    if (g >= N) return;
    int b = g >> NPB_SHIFT, n = g & (NPB - 1);
    const float4* hs4 = (const float4*)hs;
    float4 acc = hs4[(size_t)g * 4 + q];    // self loop
    const float4* p4 = (const float4*)part1;
    size_t rbase = ((size_t)b * K * NPB + n) * 4 + q;
    for (int s = 0; s < K; ++s) {
        float4 p = p4[rbase + (size_t)s * NPB * 4];
        acc.x += p.x; acc.y += p.y; acc.z += p.z; acc.w += p.w;
    }
    float di = dinv[g];
    int f0 = q * 4;
    float o0 = fmaxf(di * acc.x + b1[f0 + 0], 0.f);
    float o1 = fmaxf(di * acc.y + b1[f0 + 1], 0.f);
    float o2 = fmaxf(di * acc.z + b1[f0 + 2], 0.f);
    float o3 = fmaxf(di * acc.w + b1[f0 + 3], 0.f);
    float h0 = o0 * W2[(f0 + 0) * F2 + 0] + o1 * W2[(f0 + 1) * F2 + 0]
             + o2 * W2[(f0 + 2) * F2 + 0] + o3 * W2[(f0 + 3) * F2 + 0];
    float h1 = o0 * W2[(f0 + 0) * F2 + 1] + o1 * W2[(f0 + 1) * F2 + 1]
             + o2 * W2[(f0 + 2) * F2 + 1] + o3 * W2[(f0 + 3) * F2 + 1];
    h0 += __shfl_xor(h0, 1); h0 += __shfl_xor(h0, 2);
    h1 += __shfl_xor(h1, 1); h1 += __shfl_xor(h1, 2);
    if (q == 0) *(float2*)&hs2[(size_t)g * 2] = make_float2(di * h0, di * h1);
}

// ------- layer-2 aggregate, split-K -------
__global__ __launch_bounds__(256) void agg2_part_kernel(const int* __restrict__ bstart,
        const int* __restrict__ ebin, const float* __restrict__ hs2,
        float* __restrict__ part2, int K) {
    __shared__ float acc[NPB * 3];
    int t = threadIdx.x;
    int bid = blockIdx.x;
    int b = bid / K, slice = bid % K;
    for (int i = t; i < NPB * 3; i += 256) acc[i] = 0.f;
    __syncthreads();
    int s = bstart[b], e = bstart[b + 1];
    int len = e - s;
    int per = (len + K - 1) / K;
    int s0 = s + slice * per;
    int e0 = s0 + per; if (e0 > e) e0 = e;
    for (int i = s0 + t; i < e0; i += 256) {
        int w = ebin[i];
        int r = w >> NPB_SHIFT, cl = w & (NPB - 1);
        float2 hv = *(const float2*)&hs2[(size_t)r * 2];
        atomicAdd(&acc[cl * 3 + 0], hv.x);
        atomicAdd(&acc[cl * 3 + 1], hv.y);
    }
    __syncthreads();
    float2* p2 = (float2*)(part2 + (size_t)bid * (NPB * F2));
    for (int i = t; i < NPB; i += 256)
        p2[i] = make_float2(acc[i * 3 + 0], acc[i * 3 + 1]);
}

// ------- layer-2 combine + finalize -------
__global__ void fuse2_kernel(const float* __restrict__ part2,
        const float* __restrict__ hs2, const float* __restrict__ dinv,
        const float* __restrict__ b2, float* __restrict__ out, int N, int K) {
    int gid = blockIdx.x * blockDim.x + threadIdx.x;
    if (gid >= N * F2) return;
    int g = gid >> 1, j = gid & 1;
    int b = g >> NPB_SHIFT, n = g & (NPB - 1);
    float acc = 0.f;
    size_t rbase = ((size_t)b * K * NPB + n) * 2 + j;
    for (int s = 0; s < K; ++s) acc += part2[rbase + (size_t)s * NPB * 2];
    out[gid] = dinv[g] * (acc + hs2[gid]) + b2[j];
}

// ------- fallback direct kernels (K=1, no partial buffers) -------
__global__ __launch_bounds__(512) void agg1_kernel(const int* __restrict__ bstart,
        const int* __restrict__ ebin, const float* __restrict__ hs,
        const float* __restrict__ dinv, const float* __restrict__ b1,
        const float* __restrict__ W2, float* __restrict__ hs2, int N) {
    __shared__ float acc[NPB * 17];
    int t = threadIdx.x;
    int b = blockIdx.x;
    for (int i = t; i < NPB * 17; i += 512) acc[i] = 0.f;
    __syncthreads();
    int s = bstart[b], e = bstart[b + 1];
    int q = t & 3;
    int lane0 = t >> 2;
    const float4* hs4 = (const float4*)hs;
    for (int i = s + lane0; i < e; i += 128) {
        int w0 = ebin[i];
        int r0 = w0 >> NPB_SHIFT, c0 = w0 & (NPB - 1);
        float4 v0 = hs4[(size_t)r0 * 4 + q];
        float* a0 = &acc[c0 * 17 + q * 4];
        atomicAdd(a0 + 0, v0.x); atomicAdd(a0 + 1, v0.y);
        atomicAdd(a0 + 2, v0.z); atomicAdd(a0 + 3, v0.w);
    }
    __syncthreads();
    int n0 = b << NPB_SHIFT;
    int f0 = q * 4;
    for (int n = lane0; n < NPB; n += 128) {
        int node = n0 + n;
        if (node < N) {
            float di = dinv[node];
            float4 sv = hs4[(size_t)node * 4 + q];
            float x0 = acc[n * 17 + f0 + 0] + sv.x;
            float x1 = acc[n * 17 + f0 + 1] + sv.y;
            float x2 = acc[n * 17 + f0 + 2] + sv.z;
            float x3 = acc[n * 17 + f0 + 3] + sv.w;
            float o0 = fmaxf(di * x0 + b1[f0 + 0], 0.f);
            float o1 = fmaxf(di * x1 + b1[f0 + 1], 0.f);
            float o2 = fmaxf(di * x2 + b1[f0 + 2], 0.f);
            float o3 = fmaxf(di * x3 + b1[f0 + 3], 0.f);
            float h0 = o0 * W2[(f0 + 0) * F2 + 0] + o1 * W2[(f0 + 1) * F2 + 0]
                     + o2 * W2[(f0 + 2) * F2 + 0] + o3 * W2[(f0 + 3) * F2 + 0];
            float h1 = o0 * W2[(f0 + 0) * F2 + 1] + o1 * W2[(f0 + 1) * F2 + 1]
                     + o2 * W2[(f0 + 2) * F2 + 1] + o3 * W2[(f0 + 3) * F2 + 1];
            h0 += __shfl_xor(h0, 1); h0 += __shfl_xor(h0, 2);
            h1 += __shfl_xor(h1, 1); h1 += __shfl_xor(h1, 2);
            if (q == 0) *(float2*)&hs2[(size_t)node * 2] = make_float2(di * h0, di * h1);
        }
    }
}

__global__ __launch_bounds__(512) void agg2_kernel(const int* __restrict__ bstart,
        const int* __restrict__ ebin, const float* __restrict__ hs2,
        const float* __restrict__ dinv, const float* __restrict__ b2,
        float* __restrict__ out, int N) {
    __shared__ float acc[NPB * 3];
    int t = threadIdx.x;
    int b = blockIdx.x;
    for (int i = t; i < NPB * 3; i += 512) acc[i] = 0.f;
    __syncthreads();
    int s = bstart[b], e = bstart[b + 1];
    for (int i = s + t; i < e; i += 512) {
        int w = ebin[i];
        int r = w >> NPB_SHIFT, cl = w & (NPB - 1);
        float2 hv = *(const float2*)&hs2[(size_t)r * 2];
        atomicAdd(&acc[cl * 3 + 0], hv.x);
        atomicAdd(&acc[cl * 3 + 1], hv.y);
    }
    __syncthreads();
    int n0 = b << NPB_SHIFT;
    int j = t & 1;
    for (int n = t >> 1; n < NPB; n += 256) {
        int node = n0 + n;
        if (node < N)
            out[(size_t)node * 2 + j] =
                dinv[node] * (acc[n * 3 + j] + hs2[(size_t)node * 2 + j]) + b2[j];
    }
}

extern "C" void kernel_launch(void* const* d_in, const int* in_sizes, int n_in,
                              void* d_out, int out_size, void* d_ws, size_t ws_size,
                              hipStream_t stream) {
    const float* x  = (const float*)d_in[0];
    const int*   ei = (const int*)d_in[1];
    const float* W1 = (const float*)d_in[2];
    const float* b1 = (const float*)d_in[3];
    const float* W2 = (const float*)d_in[4];
    const float* b2 = (const float*)d_in[5];
    int N = in_sizes[0] / N_FEAT;
    int E = in_sizes[1] / 2;
    const int* rowi = ei;        // edge_index[0] = src
    const int* coli = ei + E;    // edge_index[1] = dst
    float* out = (float*)d_out;

    int nbuck = (N + NPB - 1) >> NPB_SHIFT;   // 196 for N=100000 (<= BMAX)

    // workspace layout (4B units)
    size_t NP = ((size_t)N + 1023) & ~(size_t)1023;
    size_t EP = ((size_t)E + 1023) & ~(size_t)1023;
    int*   wsI    = (int*)d_ws;
    int*   deg    = wsI;                          // NP
    float* dinv   = (float*)(wsI + NP);           // NP
    int*   bcnt   = wsI + 2 * NP;                 // 512
    int*   bstart = wsI + 2 * NP + 512;           // 512
    int*   gcur   = wsI + 2 * NP + 1024;          // 512
    float* hs     = (float*)(wsI + 2 * NP + 2048);// 16*NP
    float* hs2    = hs + 16 * NP;                 // 2*NP
    int*   ebin   = (int*)(hs2 + 2 * NP);         // EP
    float* part1  = (float*)(ebin + EP);          // K*nbuck*NPB*F1
    size_t base   = 2 * NP + 2048 + 18 * NP + EP; // 4B units used so far

    // pick largest K whose partial buffers fit the workspace
    int K = 8;
    while (K >= 1) {
        size_t need = base + (size_t)K * nbuck * (NPB * F1 + NPB * F2);
        if (need * 4 <= ws_size) break;
        K >>= 1;
    }
    float* part2 = (K >= 1) ? part1 + (size_t)K * nbuck * NPB * F1 : nullptr;

    hipMemsetAsync(deg, 0, (size_t)N * sizeof(int), stream);
    hipMemsetAsync(bcnt, 0, BMAX * sizeof(int), stream);

    deghist_kernel<<<((E + 3) / 4 + 255) / 256, 256, 0, stream>>>(coli, E, deg, bcnt);
    dinv_kernel<<<(N + 255) / 256, 256, 0, stream>>>(deg, dinv, N);
    bscan_kernel<<<1, BMAX, 0, stream>>>(bcnt, bstart, gcur, E, nbuck);
    bin_kernel<<<(E + CHUNK - 1) / CHUNK, 256, 0, stream>>>(rowi, coli, gcur, ebin, E);
    gemm1_kernel<<<(N + 15) / 16, 256, 0, stream>>>(x, W1, dinv, hs, N);

    if (K >= 2) {
        agg1_part_kernel<<<nbuck * K, 512, 0, stream>>>(bstart, ebin, hs, part1, K);
        fuse1_kernel<<<(N * 4 + 255) / 256, 256, 0, stream>>>(part1, hs, dinv, b1, W2, hs2, N, K);
        agg2_part_kernel<<<nbuck * K, 256, 0, stream>>>(bstart, ebin, hs2, part2, K);
        fuse2_kernel<<<(N * 2 + 255) / 256, 256, 0, stream>>>(part2, hs2, dinv, b2, out, N, K);
    } else {
        agg1_kernel<<<nbuck, 512, 0, stream>>>(bstart, ebin, hs, dinv, b1, W2, hs2, N);
        agg2_kernel<<<nbuck, 512, 0, stream>>>(bstart, ebin, hs2, dinv, b2, out, N);
    }
}